// Round 7
// baseline (344.168 us; speedup 1.0000x reference)
//
#include <hip/hip_runtime.h>

#define BN_EPS 1e-5f
#define SCAN_CHUNK 2048
#define EPB 4096           // edges per sort block (256 thr x 16 edges)
#define NBUCK 512          // dst>>8 buckets (dst < 131072)

// ---------------- bf16 helpers ----------------
__device__ __forceinline__ float bf2f(unsigned short u) {
  return __uint_as_float(((unsigned)u) << 16);
}
__device__ __forceinline__ unsigned short f2bf(float f) {
  unsigned b = __float_as_uint(f);
  b += 0x7FFFu + ((b >> 16) & 1u);   // round-to-nearest-even
  return (unsigned short)(b >> 16);
}

// ---------------- shared GEMM tile body ----------------
// X staged in LDS (burst of 8 float4/thread -> deep MLP, then barrier).
// W read direct from global with an explicit 2-deep register double-buffer.
// Round-7 remap: row = (lane&15)+16r, col0 = wave*16 + ((t>>4)&3)*4.
// -> the 16 row-lanes of each quarter-group share ONE W address per kk
//    (W L1 traffic 512KB -> 32KB per block; W read exactly once per block),
// -> Xs lane stride = 132 dwords = 4 mod 32 -> 8 banks x 2 lanes, conflict-free.
template<int K, bool FUSE_BN, bool SCALE>
__device__ __forceinline__ void gemm_tile(float* __restrict__ Xs,
                                          float* __restrict__ bn_s, int tile,
                                          const float* __restrict__ X,
                                          const float* __restrict__ W,
                                          const float* __restrict__ dinv,
                                          const float* __restrict__ stats,
                                          const float* __restrict__ gamma,
                                          const float* __restrict__ beta,
                                          unsigned short* __restrict__ Y,
                                          int n, float inv_n) {
  constexpr int XS = K + 4;
  const int t = threadIdx.x;
  const int base = tile * 64;
  float* mean_s = bn_s;
  float* scl_s  = bn_s + 64;
  float* bt_s   = bn_s + 128;

  if (FUSE_BN) {
    if (t < 64) {
      float mean = stats[t] * inv_n;
      float var = stats[64 + t] * inv_n - mean * mean;
      mean_s[t] = mean;
      scl_s[t] = rsqrtf(var + BN_EPS) * gamma[t];
      bt_s[t] = beta[t];
    }
    __syncthreads();
  }

  {
    constexpr int RV = K / 4;
    for (int idx = t; idx < 64 * RV; idx += 256) {
      int row = idx / RV, kk = idx % RV;
      float4 v = make_float4(0.f, 0.f, 0.f, 0.f);
      if (base + row < n) {
        v = *(const float4*)(X + (size_t)(base + row) * K + kk * 4);
        if (FUSE_BN) {
          int k0 = kk * 4;
          v.x = fmaxf(fmaf(v.x - mean_s[k0 + 0], scl_s[k0 + 0], bt_s[k0 + 0]), 0.f);
          v.y = fmaxf(fmaf(v.y - mean_s[k0 + 1], scl_s[k0 + 1], bt_s[k0 + 1]), 0.f);
          v.z = fmaxf(fmaf(v.z - mean_s[k0 + 2], scl_s[k0 + 2], bt_s[k0 + 2]), 0.f);
          v.w = fmaxf(fmaf(v.w - mean_s[k0 + 3], scl_s[k0 + 3], bt_s[k0 + 3]), 0.f);
        }
      }
      *(float4*)(Xs + row * XS + kk * 4) = v;
    }
  }
  __syncthreads();

  const int tr16 = t & 15;          // row lane: rows tr16, tr16+16, +32, +48
  const int tcw  = (t >> 4) & 3;   // col subgroup within wave
  const int w    = t >> 6;         // wave id
  const int col0 = w * 16 + tcw * 4;
  const float* wp = W + col0;

  float acc[4][4];
#pragma unroll
  for (int r = 0; r < 4; ++r)
#pragma unroll
    for (int c = 0; c < 4; ++c) acc[r][c] = 0.f;

  float4 wc[4], wn[4];
#pragma unroll
  for (int kk = 0; kk < 4; ++kk) wc[kk] = *(const float4*)(wp + kk * 64);

#pragma unroll 4
  for (int k = 0; k < K; k += 4) {
    float4 xr[4];
#pragma unroll
    for (int r = 0; r < 4; ++r) xr[r] = *(const float4*)(Xs + (tr16 + 16 * r) * XS + k);
    if (k + 4 < K) {
#pragma unroll
      for (int kk = 0; kk < 4; ++kk) wn[kk] = *(const float4*)(wp + (k + 4 + kk) * 64);
    }
#pragma unroll
    for (int kk = 0; kk < 4; ++kk) {
#pragma unroll
      for (int r = 0; r < 4; ++r) {
        float xv = (kk == 0) ? xr[r].x : (kk == 1) ? xr[r].y : (kk == 2) ? xr[r].z : xr[r].w;
        acc[r][0] = fmaf(xv, wc[kk].x, acc[r][0]);
        acc[r][1] = fmaf(xv, wc[kk].y, acc[r][1]);
        acc[r][2] = fmaf(xv, wc[kk].z, acc[r][2]);
        acc[r][3] = fmaf(xv, wc[kk].w, acc[r][3]);
      }
    }
    if (k + 4 < K) {
#pragma unroll
      for (int kk = 0; kk < 4; ++kk) wc[kk] = wn[kk];
    }
  }

#pragma unroll
  for (int r = 0; r < 4; ++r) {
    int i = base + tr16 + 16 * r;
    if (i < n) {
      float sc = SCALE ? dinv[i] : 1.0f;
      ushort4 o;
      o.x = f2bf(acc[r][0] * sc);
      o.y = f2bf(acc[r][1] * sc);
      o.z = f2bf(acc[r][2] * sc);
      o.w = f2bf(acc[r][3] * sc);
      *(ushort4*)(Y + (size_t)i * 64 + col0) = o;
    }
  }
}

// ---------------- fused: bucket histogram (LDS-only atomics) || GEMM1 ----------------
// Round 2/3 evidence: global atomic-with-return executes memory-side (32B
// fabric RMW per op, ~1.1 TB/s wall). Counting sort instead: pass A builds
// per-(block,bucket) counts with LDS atomics and plain global stores only.
__global__ __launch_bounds__(256) void k_fused_hist_gemm1(
    const int* __restrict__ dst, int* __restrict__ bh, int E, int nba,
    const float* __restrict__ X, const float* __restrict__ W,
    unsigned short* __restrict__ Y, int n, int nbT) {
  __shared__ float Xs[64 * 132];

  int paired = 2 * (nba < nbT ? nba : nbT);
  int role, idx;
  if ((int)blockIdx.x < paired) {
    role = blockIdx.x & 1;
    idx = blockIdx.x >> 1;
  } else {
    int r = blockIdx.x - paired;
    if (nba > nbT) { role = 0; idx = nbT + r; }
    else           { role = 1; idx = nba + r; }
  }

  if (role == 0) {
    int* hist = (int*)Xs;                 // overlay: role-exclusive
    const int t = threadIdx.x;
    for (int b = t; b < NBUCK; b += 256) hist[b] = 0;
    __syncthreads();
    int ebase = idx * EPB;
#pragma unroll
    for (int i = 0; i < EPB / 1024; ++i) {
      int e = ebase + (i * 256 + t) * 4;
      if (e + 3 < E) {
        int4 d4 = *(const int4*)(dst + e);
        atomicAdd(&hist[d4.x >> 8], 1);
        atomicAdd(&hist[d4.y >> 8], 1);
        atomicAdd(&hist[d4.z >> 8], 1);
        atomicAdd(&hist[d4.w >> 8], 1);
      } else {
        for (int q = e; q < E && q < e + 4; ++q) atomicAdd(&hist[dst[q] >> 8], 1);
      }
    }
    __syncthreads();
    for (int b = t; b < NBUCK; b += 256) bh[(size_t)b * nba + idx] = hist[b];
    return;
  }
  gemm_tile<128, false, false>(Xs, nullptr, idx, X, W,
                               nullptr, nullptr, nullptr, nullptr, Y, n, 0.f);
}

// ---------------- parallel exclusive scan of the 512 x nba count matrix ------
// Round-4 lesson: a single-block serial scan of the matrix cost 89 us.
__global__ __launch_bounds__(256) void k_bscan_local(int* __restrict__ a,
                                                     int* __restrict__ bsum, int M) {
  __shared__ int ts[256];
  int base = blockIdx.x * SCAN_CHUNK;
  int t = threadIdx.x;
  int idx0 = base + t * 8;
  int v[8];
  int s = 0;
#pragma unroll
  for (int k = 0; k < 8; ++k) {
    int i = idx0 + k;
    int d = (i < M) ? a[i] : 0;
    v[k] = s;
    s += d;
  }
  int val = s;
  ts[t] = val;
  __syncthreads();
#pragma unroll
  for (int off = 1; off < 256; off <<= 1) {
    int add = (t >= off) ? ts[t - off] : 0;
    __syncthreads();
    val += add;
    ts[t] = val;
    __syncthreads();
  }
  int excl = val - s;
#pragma unroll
  for (int k = 0; k < 8; ++k) {
    int i = idx0 + k;
    if (i < M) a[i] = excl + v[k];
  }
  if (t == 255) bsum[blockIdx.x] = val;
}

__global__ void k_bscan_blk(int* __restrict__ bsum, int nblk) {
  if (threadIdx.x == 0) {
    int run = 0;
    for (int i = 0; i < nblk; ++i) { int v = bsum[i]; bsum[i] = run; run += v; }
  }
}

__global__ __launch_bounds__(256) void k_bscan_add(int* __restrict__ a,
                                                   const int* __restrict__ bsum, int M) {
  int off = bsum[blockIdx.x];
  int base = blockIdx.x * SCAN_CHUNK;
  for (int k = threadIdx.x; k < SCAN_CHUNK; k += 256) {
    int i = base + k;
    if (i < M) a[i] += off;
  }
}

// ---------------- scatter edges into bucket-grouped order ----------------
// sval[pos] = src | (dst&255)<<20 ; (block,bucket) segments are contiguous.
__global__ __launch_bounds__(256) void k_scatter(
    const int* __restrict__ src, const int* __restrict__ dst,
    const int* __restrict__ bh, int* __restrict__ sval, int E, int nba) {
  __shared__ int cur[NBUCK];
  const int t = threadIdx.x;
  for (int b = t; b < NBUCK; b += 256) cur[b] = bh[(size_t)b * nba + blockIdx.x];
  __syncthreads();
  int ebase = blockIdx.x * EPB;
#pragma unroll
  for (int i = 0; i < EPB / 1024; ++i) {
    int e = ebase + (i * 256 + t) * 4;
    if (e + 3 < E) {
      int4 d4 = *(const int4*)(dst + e);
      int4 s4 = *(const int4*)(src + e);
      int p0 = atomicAdd(&cur[d4.x >> 8], 1);
      int p1 = atomicAdd(&cur[d4.y >> 8], 1);
      int p2 = atomicAdd(&cur[d4.z >> 8], 1);
      int p3 = atomicAdd(&cur[d4.w >> 8], 1);
      sval[p0] = s4.x | ((d4.x & 255) << 20);
      sval[p1] = s4.y | ((d4.y & 255) << 20);
      sval[p2] = s4.z | ((d4.z & 255) << 20);
      sval[p3] = s4.w | ((d4.w & 255) << 20);
    } else {
      for (int q = e; q < E && q < e + 4; ++q) {
        int d = dst[q];
        int p = atomicAdd(&cur[d >> 8], 1);
        sval[p] = src[q] | ((d & 255) << 20);
      }
    }
  }
}

// ---------------- exact per-node degree: one block per bucket ----------------
__global__ __launch_bounds__(256) void k_group_deg(
    const int* __restrict__ sval, const int* __restrict__ bh,
    int* __restrict__ deg, int nba, int n) {
  __shared__ int cnt[256];
  const int t = threadIdx.x;
  const int b = blockIdx.x;
  cnt[t] = 0;
  __syncthreads();
  int lo = bh[(size_t)b * nba];
  int end = bh[(size_t)(b + 1) * nba];
  for (int i = lo + t; i < end; i += 256)
    atomicAdd(&cnt[(sval[i] >> 20) & 255], 1);
  __syncthreads();
  int node = b * 256 + t;
  if (node < n) deg[node] = cnt[t];
}

// ---------------- exclusive scan (deg -> row_ptr), fused dinv ----------------

__global__ __launch_bounds__(256) void k_scan_local(const int* __restrict__ deg,
                                                    int* __restrict__ row_ptr,
                                                    int* __restrict__ blksum,
                                                    float* __restrict__ dinv, int n) {
  __shared__ int ts[256];
  int base = blockIdx.x * SCAN_CHUNK;
  int t = threadIdx.x;
  int idx0 = base + t * 8;
  int v[8];
  int s = 0;
#pragma unroll
  for (int k = 0; k < 8; ++k) {
    int i = idx0 + k;
    int d = (i < n) ? deg[i] : 0;
    if (i < n) dinv[i] = rsqrtf(1.0f + (float)d);   // self-loop included
    v[k] = s;
    s += d;
  }
  int val = s;
  ts[t] = val;
  __syncthreads();
#pragma unroll
  for (int off = 1; off < 256; off <<= 1) {
    int add = (t >= off) ? ts[t - off] : 0;
    __syncthreads();
    val += add;
    ts[t] = val;
    __syncthreads();
  }
  int excl = val - s;
#pragma unroll
  for (int k = 0; k < 8; ++k) {
    int i = idx0 + k;
    if (i < n) row_ptr[i] = excl + v[k];
  }
  if (t == 255) blksum[blockIdx.x] = val;
}

__global__ void k_scan_blk(int* __restrict__ blksum, int nblk,
                           int* __restrict__ row_ptr, int n,
                           float* __restrict__ stats) {
  for (int i = threadIdx.x; i < 128; i += 64) stats[i] = 0.f;   // fused BN-stats zero
  if (threadIdx.x == 0) {
    int run = 0;
    for (int i = 0; i < nblk; ++i) { int v = blksum[i]; blksum[i] = run; run += v; }
    row_ptr[n] = run;
  }
}

__global__ __launch_bounds__(256) void k_scan_add(int* __restrict__ row_ptr,
                                                  const int* __restrict__ blksum, int n) {
  int off = blksum[blockIdx.x];
  int base = blockIdx.x * SCAN_CHUNK;
  for (int k = threadIdx.x; k < SCAN_CHUNK; k += 256) {
    int i = base + k;
    if (i < n) row_ptr[i] += off;
  }
}

// ---------------- fused: CSR fill (per-bucket, LDS cursors) || table row-scale ----
__global__ __launch_bounds__(256) void k_fused_fill_scale(
    const int* __restrict__ sval, const int* __restrict__ bh,
    const int* __restrict__ row_ptr, int* __restrict__ col, int nba, int nbu,
    unsigned short* __restrict__ h16, const float* __restrict__ dinv, int n) {
  __shared__ int cur[256];
  const int t = threadIdx.x;
  if ((int)blockIdx.x < nbu) {
    const int b = blockIdx.x;
    int node = b * 256 + t;
    cur[t] = (node < n) ? row_ptr[node] : 0;
    __syncthreads();
    int lo = bh[(size_t)b * nba];
    int end = bh[(size_t)(b + 1) * nba];
    for (int i = lo + t; i < end; i += 256) {
      int v = sval[i];
      int p = atomicAdd(&cur[(v >> 20) & 255], 1);
      col[p] = v & 0x1FFFF;
    }
    return;
  }
  int si = blockIdx.x - nbu;
  int idx = (si * 256 + t) * 8;
  if (idx >= n * 64) return;
  int row = idx >> 6;
  float di = dinv[row];
  uint4 v = *(const uint4*)(h16 + idx);
  unsigned r[4] = {v.x, v.y, v.z, v.w};
#pragma unroll
  for (int q = 0; q < 4; ++q) {
    float lo = bf2f((unsigned short)(r[q] & 0xFFFFu)) * di;
    float hi = bf2f((unsigned short)(r[q] >> 16)) * di;
    r[q] = ((unsigned)f2bf(hi) << 16) | f2bf(lo);
  }
  *(uint4*)(h16 + idx) = make_uint4(r[0], r[1], r[2], r[3]);
}

// ---------------- quad-gather: one row/wave, FOUR rows per load slot ----------
// Round-5 lesson: pair-gather was tail-latency-bound. (1) neighbor ids in
// registers (in-loop col reads are __shfl), (2) uint2 loads: 4 rows per wave
// instruction, (3) masked final round instead of serial tail.
__global__ __launch_bounds__(256) void k_gather_quad(
    const unsigned short* __restrict__ Hs,
    const int* __restrict__ row_ptr,
    const int* __restrict__ col,
    const float* __restrict__ dinv,
    const float* __restrict__ b,
    float* __restrict__ out, int n) {
  const uint2* H64 = (const uint2*)Hs;
  int lane = threadIdx.x & 63;
  int wv = threadIdx.x >> 6;
  int i = blockIdx.x * 4 + wv;
  if (i >= n) return;
  int quarter = lane >> 4;
  int q = lane & 15;
  int p0 = row_ptr[i], p1 = row_ptr[i + 1];
  int nl = p1 - p0;
  int L = nl + 1;                       // self + neighbors
  int cl = (lane == 0) ? i : ((lane <= nl) ? col[p0 + lane - 1] : i);
  float a0 = 0.f, a1 = 0.f, a2 = 0.f, a3 = 0.f;
  int Lc = (L < 64) ? L : 64;
  int k = 0;
  for (; k + 16 <= Lc; k += 16) {
#pragma unroll
    for (int j = 0; j < 4; ++j) {
      int c = __shfl(cl, k + quarter * 4 + j);
      uint2 u = H64[(size_t)c * 16 + q];
      a0 += bf2f((unsigned short)u.x);
      a1 += bf2f((unsigned short)(u.x >> 16));
      a2 += bf2f((unsigned short)u.y);
      a3 += bf2f((unsigned short)(u.y >> 16));
    }
  }
  if (k < Lc) {                          // masked final round
#pragma unroll
    for (int j = 0; j < 4; ++j) {
      int vidx = k + quarter * 4 + j;
      int vc = (vidx < Lc) ? vidx : (Lc - 1);
      int c = __shfl(cl, vc);
      uint2 u = H64[(size_t)c * 16 + q];
      float w = (vidx < Lc) ? 1.0f : 0.0f;
      a0 = fmaf(w, bf2f((unsigned short)u.x), a0);
      a1 = fmaf(w, bf2f((unsigned short)(u.x >> 16)), a1);
      a2 = fmaf(w, bf2f((unsigned short)u.y), a2);
      a3 = fmaf(w, bf2f((unsigned short)(u.y >> 16)), a3);
    }
  }
  for (int v = 64 + quarter; v < L; v += 4) {   // rare: degree > 63
    int c = col[p0 + v - 1];
    uint2 u = H64[(size_t)c * 16 + q];
    a0 += bf2f((unsigned short)u.x);
    a1 += bf2f((unsigned short)(u.x >> 16));
    a2 += bf2f((unsigned short)u.y);
    a3 += bf2f((unsigned short)(u.y >> 16));
  }
  a0 += __shfl_down(a0, 16); a0 += __shfl_down(a0, 32);
  a1 += __shfl_down(a1, 16); a1 += __shfl_down(a1, 32);
  a2 += __shfl_down(a2, 16); a2 += __shfl_down(a2, 32);
  a3 += __shfl_down(a3, 16); a3 += __shfl_down(a3, 32);
  if (lane < 16) {
    float di = dinv[i];
    float4 bb = *(const float4*)(b + 4 * q);
    float4 o;
    o.x = fmaf(di, a0, bb.x);
    o.y = fmaf(di, a1, bb.y);
    o.z = fmaf(di, a2, bb.z);
    o.w = fmaf(di, a3, bb.w);
    *(float4*)(out + (size_t)i * 64 + 4 * q) = o;
  }
}

// ---------------- BatchNorm stats (separate pass) ----------------
__global__ __launch_bounds__(256) void k_bnstats(const float* __restrict__ A,
                                                 float* __restrict__ stats, int n) {
  int j = threadIdx.x & 63;
  int r = threadIdx.x >> 6;
  float s = 0.f, s2 = 0.f;
  for (int i = blockIdx.x * 4 + r; i < n; i += gridDim.x * 4) {
    float v = A[(size_t)i * 64 + j];
    s += v;
    s2 += v * v;
  }
  __shared__ float ls[256], ls2[256];
  ls[threadIdx.x] = s;
  ls2[threadIdx.x] = s2;
  __syncthreads();
  if (threadIdx.x < 64) {
    atomicAdd(&stats[j], ls[j] + ls[j + 64] + ls[j + 128] + ls[j + 192]);
    atomicAdd(&stats[64 + j], ls2[j] + ls2[j + 64] + ls2[j + 128] + ls2[j + 192]);
  }
}

// ---------------- GEMM2 standalone (BN+ReLU fused input, dinv-scaled output) ----------------
__global__ __launch_bounds__(256) void k_gemm2(const float* __restrict__ X,
                                               const float* __restrict__ W,
                                               const float* __restrict__ dinv,
                                               const float* __restrict__ stats,
                                               const float* __restrict__ gamma,
                                               const float* __restrict__ beta,
                                               unsigned short* __restrict__ Y,
                                               int n, float inv_n) {
  __shared__ float Xs[64 * 68];
  __shared__ float bn_s[192];
  gemm_tile<64, true, true>(Xs, bn_s, blockIdx.x, X, W, dinv, stats, gamma, beta,
                            Y, n, inv_n);
}

// ---------------- launch ----------------

extern "C" void kernel_launch(void* const* d_in, const int* in_sizes, int n_in,
                              void* d_out, int out_size, void* d_ws, size_t ws_size,
                              hipStream_t stream) {
  const float* x     = (const float*)d_in[0];
  const int*   ei    = (const int*)d_in[1];
  const float* W1    = (const float*)d_in[2];
  const float* b1    = (const float*)d_in[3];
  const float* W2    = (const float*)d_in[4];
  const float* b2    = (const float*)d_in[5];
  const float* gamma = (const float*)d_in[6];
  const float* beta  = (const float*)d_in[7];
  float* out = (float*)d_out;

  const int N = in_sizes[0] / 128;   // 100000
  const int E = in_sizes[1] / 2;     // 1600000
  const int* src = ei;
  const int* dst = ei + E;

  const size_t Npad = ((size_t)N + 256) & ~(size_t)255;

  // workspace layout (identical footprint to previous rounds)
  char* p = (char*)d_ws;
  float* dinv    = (float*)p;               p += Npad * 4;
  int*   deg     = (int*)p;                 p += Npad * 4;
  int*   row_ptr = (int*)p;                 p += Npad * 4;
  int*   blksum  = (int*)p;                 p += 256 * 4;
  int*   sval    = (int*)p;                 p += (size_t)E * 4;   // bucket-grouped edges
  int*   col     = (int*)p;                 p += (size_t)E * 4;
  unsigned short* h16 = (unsigned short*)p; p += (size_t)N * 64 * 2;  // bf16 table
  float* agg     = (float*)p;               p += (size_t)N * 64 * 4;
  float* stats   = (float*)p;               p += 128 * 4;

  // bh aliases agg: bh dies after k_fused_fill_scale, agg born at gather1.
  int* bh = (int*)agg;                      // NBUCK * nba ints (~800 KB)

  int nb_n4 = (N + 3) / 4;
  int nb_t  = (N + 63) / 64;
  int nba   = (E + EPB - 1) / EPB;               // sort blocks (391)
  int nbu   = (N + 255) / 256;                   // used buckets (391)
  int nbS   = (N * 64 + 2047) / 2048;            // 8 bf16 elems/thread
  int nscan = (N + SCAN_CHUNK - 1) / SCAN_CHUNK;
  int M     = NBUCK * nba;                       // count-matrix size (~200K)
  int nbM   = (M + SCAN_CHUNK - 1) / SCAN_CHUNK; // ~98 blocks
  float inv_n = 1.0f / (float)N;

  // ---- fused: bucket histogram || GEMM1 ----
  k_fused_hist_gemm1<<<nba + nb_t, 256, 0, stream>>>(dst, bh, E, nba,
                                                     x, W1, h16, N, nb_t);

  // ---- counting sort: 3-phase parallel scan of count matrix, then scatter ----
  k_bscan_local<<<nbM, 256, 0, stream>>>(bh, blksum, M);
  k_bscan_blk<<<1, 64, 0, stream>>>(blksum, nbM);
  k_bscan_add<<<nbM, 256, 0, stream>>>(bh, blksum, M);
  k_scatter<<<nba, 256, 0, stream>>>(src, dst, bh, sval, E, nba);

  // ---- exact per-node degree (no global atomics) ----
  k_group_deg<<<nbu, 256, 0, stream>>>(sval, bh, deg, nba, N);

  // ---- CSR scan (dinv fused; stats zero fused) ----
  k_scan_local<<<nscan, 256, 0, stream>>>(deg, row_ptr, blksum, dinv, N);
  k_scan_blk<<<1, 64, 0, stream>>>(blksum, nscan, row_ptr, N, stats);
  k_scan_add<<<nscan, 256, 0, stream>>>(row_ptr, blksum, N);

  // ---- fused: CSR fill (bucket-local) || table row-scale ----
  k_fused_fill_scale<<<nbu + nbS, 256, 0, stream>>>(sval, bh, row_ptr, col,
                                                    nba, nbu, h16, dinv, N);

  // ---- layer 1 aggregation (quad loads, shfl col cache) ----
  k_gather_quad<<<nb_n4, 256, 0, stream>>>(h16, row_ptr, col, dinv, b1, agg, N);

  // ---- BN stats ----
  k_bnstats<<<1024, 256, 0, stream>>>(agg, stats, N);

  // ---- layer 2: BN+ReLU fused GEMM -> scaled bf16 table; quad gather ----
  k_gemm2<<<nb_t, 256, 0, stream>>>(agg, W2, dinv, stats, gamma, beta, h16, N, inv_n);
  k_gather_quad<<<nb_n4, 256, 0, stream>>>(h16, row_ptr, col, dinv, b2, out, N);
}

// Round 9
// 337.604 us; speedup vs baseline: 1.0194x; 1.0194x over previous
//
#include <hip/hip_runtime.h>

#define BN_EPS 1e-5f
#define SCAN_CHUNK 2048
#define EPB 16384          // edges per sort block (256 thr x 64 edges)
#define NBUCK 512          // dst>>8 buckets (dst < 131072)

// ---------------- bf16 helpers ----------------
__device__ __forceinline__ float bf2f(unsigned short u) {
  return __uint_as_float(((unsigned)u) << 16);
}
__device__ __forceinline__ unsigned short f2bf(float f) {
  unsigned b = __float_as_uint(f);
  b += 0x7FFFu + ((b >> 16) & 1u);   // round-to-nearest-even
  return (unsigned short)(b >> 16);
}

// ---------------- shared GEMM tile body (round-6 proven layout) ----------------
// X staged in LDS (burst of 8 float4/thread -> deep MLP, then barrier).
// W read direct from global with an explicit 2-deep register double-buffer
// (round-1 lesson: low VGPR = serialized loads).
template<int K, bool FUSE_BN, bool SCALE>
__device__ __forceinline__ void gemm_tile(float* __restrict__ Xs,
                                          float* __restrict__ bn_s, int tile,
                                          const float* __restrict__ X,
                                          const float* __restrict__ W,
                                          const float* __restrict__ dinv,
                                          const float* __restrict__ stats,
                                          const float* __restrict__ gamma,
                                          const float* __restrict__ beta,
                                          unsigned short* __restrict__ Y,
                                          int n, float inv_n) {
  constexpr int XS = K + 4;
  const int t = threadIdx.x;
  const int base = tile * 64;
  float* mean_s = bn_s;
  float* scl_s  = bn_s + 64;
  float* bt_s   = bn_s + 128;

  if (FUSE_BN) {
    if (t < 64) {
      float mean = stats[t] * inv_n;
      float var = stats[64 + t] * inv_n - mean * mean;
      mean_s[t] = mean;
      scl_s[t] = rsqrtf(var + BN_EPS) * gamma[t];
      bt_s[t] = beta[t];
    }
    __syncthreads();
  }

  {
    constexpr int RV = K / 4;
    for (int idx = t; idx < 64 * RV; idx += 256) {
      int row = idx / RV, kk = idx % RV;
      float4 v = make_float4(0.f, 0.f, 0.f, 0.f);
      if (base + row < n) {
        v = *(const float4*)(X + (size_t)(base + row) * K + kk * 4);
        if (FUSE_BN) {
          int k0 = kk * 4;
          v.x = fmaxf(fmaf(v.x - mean_s[k0 + 0], scl_s[k0 + 0], bt_s[k0 + 0]), 0.f);
          v.y = fmaxf(fmaf(v.y - mean_s[k0 + 1], scl_s[k0 + 1], bt_s[k0 + 1]), 0.f);
          v.z = fmaxf(fmaf(v.z - mean_s[k0 + 2], scl_s[k0 + 2], bt_s[k0 + 2]), 0.f);
          v.w = fmaxf(fmaf(v.w - mean_s[k0 + 3], scl_s[k0 + 3], bt_s[k0 + 3]), 0.f);
        }
      }
      *(float4*)(Xs + row * XS + kk * 4) = v;
    }
  }
  __syncthreads();

  const int tc = t & 15;
  const int tr = t >> 4;
  const float* wp = W + tc * 4;

  float acc[4][4];
#pragma unroll
  for (int r = 0; r < 4; ++r)
#pragma unroll
    for (int c = 0; c < 4; ++c) acc[r][c] = 0.f;

  float4 wc[4], wn[4];
#pragma unroll
  for (int kk = 0; kk < 4; ++kk) wc[kk] = *(const float4*)(wp + kk * 64);

#pragma unroll 4
  for (int k = 0; k < K; k += 4) {
    float4 xr[4];
#pragma unroll
    for (int r = 0; r < 4; ++r) xr[r] = *(const float4*)(Xs + (tr * 4 + r) * XS + k);
    if (k + 4 < K) {
#pragma unroll
      for (int kk = 0; kk < 4; ++kk) wn[kk] = *(const float4*)(wp + (k + 4 + kk) * 64);
    }
#pragma unroll
    for (int kk = 0; kk < 4; ++kk) {
#pragma unroll
      for (int r = 0; r < 4; ++r) {
        float xv = (kk == 0) ? xr[r].x : (kk == 1) ? xr[r].y : (kk == 2) ? xr[r].z : xr[r].w;
        acc[r][0] = fmaf(xv, wc[kk].x, acc[r][0]);
        acc[r][1] = fmaf(xv, wc[kk].y, acc[r][1]);
        acc[r][2] = fmaf(xv, wc[kk].z, acc[r][2]);
        acc[r][3] = fmaf(xv, wc[kk].w, acc[r][3]);
      }
    }
    if (k + 4 < K) {
#pragma unroll
      for (int kk = 0; kk < 4; ++kk) wc[kk] = wn[kk];
    }
  }

#pragma unroll
  for (int r = 0; r < 4; ++r) {
    int i = base + tr * 4 + r;
    if (i < n) {
      float sc = SCALE ? dinv[i] : 1.0f;
      ushort4 o;
      o.x = f2bf(acc[r][0] * sc);
      o.y = f2bf(acc[r][1] * sc);
      o.z = f2bf(acc[r][2] * sc);
      o.w = f2bf(acc[r][3] * sc);
      *(ushort4*)(Y + (size_t)i * 64 + tc * 4) = o;
    }
  }
}

// ---------------- fused: bucket histogram (LDS-only atomics) || GEMM1 ----------------
// Round 2/3 evidence: global atomic-with-return executes memory-side (32B
// fabric RMW per op, ~1.1 TB/s wall). Counting sort instead: pass A builds
// per-(block,bucket) counts with LDS atomics and plain global stores only.
__global__ __launch_bounds__(256) void k_fused_hist_gemm1(
    const int* __restrict__ dst, int* __restrict__ bh, int E, int nba,
    const float* __restrict__ X, const float* __restrict__ W,
    unsigned short* __restrict__ Y, int n, int nbT) {
  __shared__ float Xs[64 * 132];

  int paired = 2 * (nba < nbT ? nba : nbT);
  int role, idx;
  if ((int)blockIdx.x < paired) {
    role = blockIdx.x & 1;
    idx = blockIdx.x >> 1;
  } else {
    int r = blockIdx.x - paired;
    if (nba > nbT) { role = 0; idx = nbT + r; }
    else           { role = 1; idx = nba + r; }
  }

  if (role == 0) {
    int* hist = (int*)Xs;                 // overlay: role-exclusive
    const int t = threadIdx.x;
    for (int b = t; b < NBUCK; b += 256) hist[b] = 0;
    __syncthreads();
    int ebase = idx * EPB;
#pragma unroll
    for (int i = 0; i < EPB / 1024; ++i) {
      int e = ebase + (i * 256 + t) * 4;
      if (e + 3 < E) {
        int4 d4 = *(const int4*)(dst + e);
        atomicAdd(&hist[d4.x >> 8], 1);
        atomicAdd(&hist[d4.y >> 8], 1);
        atomicAdd(&hist[d4.z >> 8], 1);
        atomicAdd(&hist[d4.w >> 8], 1);
      } else {
        for (int q = e; q < E && q < e + 4; ++q) atomicAdd(&hist[dst[q] >> 8], 1);
      }
    }
    __syncthreads();
    for (int b = t; b < NBUCK; b += 256) bh[(size_t)b * nba + idx] = hist[b];
    return;
  }
  gemm_tile<128, false, false>(Xs, nullptr, idx, X, W,
                               nullptr, nullptr, nullptr, nullptr, Y, n, 0.f);
}

// ---------------- parallel exclusive scan of the 512 x nba count matrix ------
__global__ __launch_bounds__(256) void k_bscan_local(int* __restrict__ a,
                                                     int* __restrict__ bsum, int M) {
  __shared__ int ts[256];
  int base = blockIdx.x * SCAN_CHUNK;
  int t = threadIdx.x;
  int idx0 = base + t * 8;
  int v[8];
  int s = 0;
#pragma unroll
  for (int k = 0; k < 8; ++k) {
    int i = idx0 + k;
    int d = (i < M) ? a[i] : 0;
    v[k] = s;
    s += d;
  }
  int val = s;
  ts[t] = val;
  __syncthreads();
#pragma unroll
  for (int off = 1; off < 256; off <<= 1) {
    int add = (t >= off) ? ts[t - off] : 0;
    __syncthreads();
    val += add;
    ts[t] = val;
    __syncthreads();
  }
  int excl = val - s;
#pragma unroll
  for (int k = 0; k < 8; ++k) {
    int i = idx0 + k;
    if (i < M) a[i] = excl + v[k];
  }
  if (t == 255) bsum[blockIdx.x] = val;
}

__global__ void k_bscan_blk(int* __restrict__ bsum, int nblk) {
  if (threadIdx.x == 0) {
    int run = 0;
    for (int i = 0; i < nblk; ++i) { int v = bsum[i]; bsum[i] = run; run += v; }
  }
}

__global__ __launch_bounds__(256) void k_bscan_add(int* __restrict__ a,
                                                   const int* __restrict__ bsum, int M) {
  int off = bsum[blockIdx.x];
  int base = blockIdx.x * SCAN_CHUNK;
  for (int k = threadIdx.x; k < SCAN_CHUNK; k += 256) {
    int i = base + k;
    if (i < M) a[i] += off;
  }
}

// ---------------- scatter edges into bucket-grouped order ----------------
__global__ __launch_bounds__(256) void k_scatter(
    const int* __restrict__ src, const int* __restrict__ dst,
    const int* __restrict__ bh, int* __restrict__ sval, int E, int nba) {
  __shared__ int cur[NBUCK];
  const int t = threadIdx.x;
  for (int b = t; b < NBUCK; b += 256) cur[b] = bh[(size_t)b * nba + blockIdx.x];
  __syncthreads();
  int ebase = blockIdx.x * EPB;
#pragma unroll
  for (int i = 0; i < EPB / 1024; ++i) {
    int e = ebase + (i * 256 + t) * 4;
    if (e + 3 < E) {
      int4 d4 = *(const int4*)(dst + e);
      int4 s4 = *(const int4*)(src + e);
      int p0 = atomicAdd(&cur[d4.x >> 8], 1);
      int p1 = atomicAdd(&cur[d4.y >> 8], 1);
      int p2 = atomicAdd(&cur[d4.z >> 8], 1);
      int p3 = atomicAdd(&cur[d4.w >> 8], 1);
      sval[p0] = s4.x | ((d4.x & 255) << 20);
      sval[p1] = s4.y | ((d4.y & 255) << 20);
      sval[p2] = s4.z | ((d4.z & 255) << 20);
      sval[p3] = s4.w | ((d4.w & 255) << 20);
    } else {
      for (int q = e; q < E && q < e + 4; ++q) {
        int d = dst[q];
        int p = atomicAdd(&cur[d >> 8], 1);
        sval[p] = src[q] | ((d & 255) << 20);
      }
    }
  }
}

// ---------------- exact per-node degree: one block per bucket ----------------
__global__ __launch_bounds__(256) void k_group_deg(
    const int* __restrict__ sval, const int* __restrict__ bh,
    int* __restrict__ deg, int nba, int n) {
  __shared__ int cnt[256];
  const int t = threadIdx.x;
  const int b = blockIdx.x;
  cnt[t] = 0;
  __syncthreads();
  int lo = bh[(size_t)b * nba];
  int end = bh[(size_t)(b + 1) * nba];
  for (int i = lo + t; i < end; i += 256)
    atomicAdd(&cnt[(sval[i] >> 20) & 255], 1);
  __syncthreads();
  int node = b * 256 + t;
  if (node < n) deg[node] = cnt[t];
}

// ---------------- exclusive scan (deg -> row_ptr), fused dinv ----------------

__global__ __launch_bounds__(256) void k_scan_local(const int* __restrict__ deg,
                                                    int* __restrict__ row_ptr,
                                                    int* __restrict__ blksum,
                                                    float* __restrict__ dinv, int n) {
  __shared__ int ts[256];
  int base = blockIdx.x * SCAN_CHUNK;
  int t = threadIdx.x;
  int idx0 = base + t * 8;
  int v[8];
  int s = 0;
#pragma unroll
  for (int k = 0; k < 8; ++k) {
    int i = idx0 + k;
    int d = (i < n) ? deg[i] : 0;
    if (i < n) dinv[i] = rsqrtf(1.0f + (float)d);   // self-loop included
    v[k] = s;
    s += d;
  }
  int val = s;
  ts[t] = val;
  __syncthreads();
#pragma unroll
  for (int off = 1; off < 256; off <<= 1) {
    int add = (t >= off) ? ts[t - off] : 0;
    __syncthreads();
    val += add;
    ts[t] = val;
    __syncthreads();
  }
  int excl = val - s;
#pragma unroll
  for (int k = 0; k < 8; ++k) {
    int i = idx0 + k;
    if (i < n) row_ptr[i] = excl + v[k];
  }
  if (t == 255) blksum[blockIdx.x] = val;
}

__global__ void k_scan_blk(int* __restrict__ blksum, int nblk,
                           int* __restrict__ row_ptr, int n,
                           float* __restrict__ stats) {
  for (int i = threadIdx.x; i < 128; i += 64) stats[i] = 0.f;   // fused BN-stats zero
  if (threadIdx.x == 0) {
    int run = 0;
    for (int i = 0; i < nblk; ++i) { int v = blksum[i]; blksum[i] = run; run += v; }
    row_ptr[n] = run;
  }
}

__global__ __launch_bounds__(256) void k_scan_add(int* __restrict__ row_ptr,
                                                  const int* __restrict__ blksum, int n) {
  int off = blksum[blockIdx.x];
  int base = blockIdx.x * SCAN_CHUNK;
  for (int k = threadIdx.x; k < SCAN_CHUNK; k += 256) {
    int i = base + k;
    if (i < n) row_ptr[i] += off;
  }
}

// ---------------- fused: CSR fill (per-bucket, LDS cursors) || table row-scale ----
__global__ __launch_bounds__(256) void k_fused_fill_scale(
    const int* __restrict__ sval, const int* __restrict__ bh,
    const int* __restrict__ row_ptr, int* __restrict__ col, int nba, int nbu,
    unsigned short* __restrict__ h16, const float* __restrict__ dinv, int n) {
  __shared__ int cur[256];
  const int t = threadIdx.x;
  if ((int)blockIdx.x < nbu) {
    const int b = blockIdx.x;
    int node = b * 256 + t;
    cur[t] = (node < n) ? row_ptr[node] : 0;
    __syncthreads();
    int lo = bh[(size_t)b * nba];
    int end = bh[(size_t)(b + 1) * nba];
    for (int i = lo + t; i < end; i += 256) {
      int v = sval[i];
      int p = atomicAdd(&cur[(v >> 20) & 255], 1);
      col[p] = v & 0x1FFFF;
    }
    return;
  }
  int si = blockIdx.x - nbu;
  int idx = (si * 256 + t) * 8;
  if (idx >= n * 64) return;
  int row = idx >> 6;
  float di = dinv[row];
  uint4 v = *(const uint4*)(h16 + idx);
  unsigned r[4] = {v.x, v.y, v.z, v.w};
#pragma unroll
  for (int q = 0; q < 4; ++q) {
    float lo = bf2f((unsigned short)(r[q] & 0xFFFFu)) * di;
    float hi = bf2f((unsigned short)(r[q] >> 16)) * di;
    r[q] = ((unsigned)f2bf(hi) << 16) | f2bf(lo);
  }
  *(uint4*)(h16 + idx) = make_uint4(r[0], r[1], r[2], r[3]);
}

// ---------------- gather: round-6 semantics, pipelined loads ----------------
// Identical math to round-6's quad gather (pre-scaled table, weights 1/0,
// dinv[i] epilogue) -- ONLY the load schedule changes: the up-to-8 row loads
// (two masked 16-wide rounds) are hoisted into uint2 u[8] registers before
// any accumulation, forcing the allocator to keep them in flight (round-7
// evidence: VGPR_Count=16 meant the loads were serialized). L>32 rows use
// the strided fallback loop (covers v in [32,L) exactly).
__global__ __launch_bounds__(256) void k_gather_p(
    const unsigned short* __restrict__ Hs,
    const int* __restrict__ row_ptr,
    const int* __restrict__ col,
    const float* __restrict__ dinv,
    const float* __restrict__ b,
    float* __restrict__ out, int n) {
  const uint2* H64 = (const uint2*)Hs;
  int lane = threadIdx.x & 63;
  int wv = threadIdx.x >> 6;
  int i = blockIdx.x * 4 + wv;
  if (i >= n) return;
  int quarter = lane >> 4;
  int q = lane & 15;
  int p0 = row_ptr[i], p1 = row_ptr[i + 1];
  int nl = p1 - p0;
  int L = nl + 1;                       // self + neighbors
  int cl = (lane == 0) ? i : ((lane <= nl) ? col[p0 + lane - 1] : i);
  int Lc = (L < 32) ? L : 32;
  bool two = (Lc > 16);                 // wave-uniform

  uint2 u[8];
  float ww[8];
#pragma unroll
  for (int s = 0; s < 4; ++s) {         // round 0: vidx 0..15
    int vidx = quarter * 4 + s;
    int vc = (vidx < Lc) ? vidx : 0;    // clamp to self (L1-hit dup)
    int c = __shfl(cl, vc);
    u[s] = H64[(size_t)c * 16 + q];
    ww[s] = (vidx < Lc) ? 1.0f : 0.0f;
  }
  if (two) {
#pragma unroll
    for (int s = 4; s < 8; ++s) {       // round 1: vidx 16..31
      int vidx = 16 + quarter * 4 + (s - 4);
      int vc = (vidx < Lc) ? vidx : 0;
      int c = __shfl(cl, vc);
      u[s] = H64[(size_t)c * 16 + q];
      ww[s] = (vidx < Lc) ? 1.0f : 0.0f;
    }
  }

  float a0 = 0.f, a1 = 0.f, a2 = 0.f, a3 = 0.f;
#pragma unroll
  for (int s = 0; s < 4; ++s) {
    a0 = fmaf(ww[s], bf2f((unsigned short)u[s].x), a0);
    a1 = fmaf(ww[s], bf2f((unsigned short)(u[s].x >> 16)), a1);
    a2 = fmaf(ww[s], bf2f((unsigned short)u[s].y), a2);
    a3 = fmaf(ww[s], bf2f((unsigned short)(u[s].y >> 16)), a3);
  }
  if (two) {
#pragma unroll
    for (int s = 4; s < 8; ++s) {
      a0 = fmaf(ww[s], bf2f((unsigned short)u[s].x), a0);
      a1 = fmaf(ww[s], bf2f((unsigned short)(u[s].x >> 16)), a1);
      a2 = fmaf(ww[s], bf2f((unsigned short)u[s].y), a2);
      a3 = fmaf(ww[s], bf2f((unsigned short)(u[s].y >> 16)), a3);
    }
  }
  for (int v = 32 + quarter; v < L; v += 4) {   // rare: degree > 31
    int c = col[p0 + v - 1];
    uint2 uu = H64[(size_t)c * 16 + q];
    a0 += bf2f((unsigned short)uu.x);
    a1 += bf2f((unsigned short)(uu.x >> 16));
    a2 += bf2f((unsigned short)uu.y);
    a3 += bf2f((unsigned short)(uu.y >> 16));
  }
  a0 += __shfl_down(a0, 16); a0 += __shfl_down(a0, 32);
  a1 += __shfl_down(a1, 16); a1 += __shfl_down(a1, 32);
  a2 += __shfl_down(a2, 16); a2 += __shfl_down(a2, 32);
  a3 += __shfl_down(a3, 16); a3 += __shfl_down(a3, 32);
  if (lane < 16) {
    float di = dinv[i];
    float4 bb = *(const float4*)(b + 4 * q);
    float4 o;
    o.x = fmaf(di, a0, bb.x);
    o.y = fmaf(di, a1, bb.y);
    o.z = fmaf(di, a2, bb.z);
    o.w = fmaf(di, a3, bb.w);
    *(float4*)(out + (size_t)i * 64 + 4 * q) = o;
  }
}

// ---------------- BatchNorm stats (separate pass) ----------------
__global__ __launch_bounds__(256) void k_bnstats(const float* __restrict__ A,
                                                 float* __restrict__ stats, int n) {
  int j = threadIdx.x & 63;
  int r = threadIdx.x >> 6;
  float s = 0.f, s2 = 0.f;
  for (int i = blockIdx.x * 4 + r; i < n; i += gridDim.x * 4) {
    float v = A[(size_t)i * 64 + j];
    s += v;
    s2 += v * v;
  }
  __shared__ float ls[256], ls2[256];
  ls[threadIdx.x] = s;
  ls2[threadIdx.x] = s2;
  __syncthreads();
  if (threadIdx.x < 64) {
    atomicAdd(&stats[j], ls[j] + ls[j + 64] + ls[j + 128] + ls[j + 192]);
    atomicAdd(&stats[64 + j], ls2[j] + ls2[j + 64] + ls2[j + 128] + ls2[j + 192]);
  }
}

// ---------------- GEMM2 standalone (BN+ReLU fused input, dinv-scaled output) ----------------
__global__ __launch_bounds__(256) void k_gemm2(const float* __restrict__ X,
                                               const float* __restrict__ W,
                                               const float* __restrict__ dinv,
                                               const float* __restrict__ stats,
                                               const float* __restrict__ gamma,
                                               const float* __restrict__ beta,
                                               unsigned short* __restrict__ Y,
                                               int n, float inv_n) {
  __shared__ float Xs[64 * 68];
  __shared__ float bn_s[192];
  gemm_tile<64, true, true>(Xs, bn_s, blockIdx.x, X, W, dinv, stats, gamma, beta,
                            Y, n, inv_n);
}

// ---------------- launch ----------------

extern "C" void kernel_launch(void* const* d_in, const int* in_sizes, int n_in,
                              void* d_out, int out_size, void* d_ws, size_t ws_size,
                              hipStream_t stream) {
  const float* x     = (const float*)d_in[0];
  const int*   ei    = (const int*)d_in[1];
  const float* W1    = (const float*)d_in[2];
  const float* b1    = (const float*)d_in[3];
  const float* W2    = (const float*)d_in[4];
  const float* b2    = (const float*)d_in[5];
  const float* gamma = (const float*)d_in[6];
  const float* beta  = (const float*)d_in[7];
  float* out = (float*)d_out;

  const int N = in_sizes[0] / 128;   // 100000
  const int E = in_sizes[1] / 2;     // 1600000
  const int* src = ei;
  const int* dst = ei + E;

  const size_t Npad = ((size_t)N + 256) & ~(size_t)255;

  // workspace layout (identical footprint to previous rounds)
  char* p = (char*)d_ws;
  float* dinv    = (float*)p;               p += Npad * 4;
  int*   deg     = (int*)p;                 p += Npad * 4;
  int*   row_ptr = (int*)p;                 p += Npad * 4;
  int*   blksum  = (int*)p;                 p += 256 * 4;
  int*   sval    = (int*)p;                 p += (size_t)E * 4;   // bucket-grouped edges
  int*   col     = (int*)p;                 p += (size_t)E * 4;
  unsigned short* h16 = (unsigned short*)p; p += (size_t)N * 64 * 2;  // bf16 table
  float* agg     = (float*)p;               p += (size_t)N * 64 * 4;
  float* stats   = (float*)p;               p += 128 * 4;

  // bh aliases agg: bh dies after k_fused_fill_scale, agg born at gather1.
  int* bh = (int*)agg;                      // NBUCK * nba ints (~200 KB)

  int nb_n4 = (N + 3) / 4;
  int nb_t  = (N + 63) / 64;
  int nba   = (E + EPB - 1) / EPB;               // sort blocks (98)
  int nbu   = (N + 255) / 256;                   // used buckets (391)
  int nbS   = (N * 64 + 2047) / 2048;            // 8 bf16 elems/thread
  int nscan = (N + SCAN_CHUNK - 1) / SCAN_CHUNK;
  int M     = NBUCK * nba;                       // count-matrix size (50176)
  int nbM   = (M + SCAN_CHUNK - 1) / SCAN_CHUNK; // 25 blocks
  float inv_n = 1.0f / (float)N;

  // ---- fused: bucket histogram || GEMM1 ----
  k_fused_hist_gemm1<<<nba + nb_t, 256, 0, stream>>>(dst, bh, E, nba,
                                                     x, W1, h16, N, nb_t);

  // ---- counting sort: 3-phase parallel scan of count matrix, then scatter ----
  k_bscan_local<<<nbM, 256, 0, stream>>>(bh, blksum, M);
  k_bscan_blk<<<1, 64, 0, stream>>>(blksum, nbM);
  k_bscan_add<<<nbM, 256, 0, stream>>>(bh, blksum, M);
  k_scatter<<<nba, 256, 0, stream>>>(src, dst, bh, sval, E, nba);

  // ---- exact per-node degree (no global atomics) ----
  k_group_deg<<<nbu, 256, 0, stream>>>(sval, bh, deg, nba, N);

  // ---- CSR scan (dinv fused; stats zero fused) ----
  k_scan_local<<<nscan, 256, 0, stream>>>(deg, row_ptr, blksum, dinv, N);
  k_scan_blk<<<1, 64, 0, stream>>>(blksum, nscan, row_ptr, N, stats);
  k_scan_add<<<nscan, 256, 0, stream>>>(row_ptr, blksum, N);

  // ---- fused: CSR fill (bucket-local) || table row-scale ----
  k_fused_fill_scale<<<nbu + nbS, 256, 0, stream>>>(sval, bh, row_ptr, col,
                                                    nba, nbu, h16, dinv, N);

  // ---- layer 1 aggregation (pipelined loads, shfl col cache) ----
  k_gather_p<<<nb_n4, 256, 0, stream>>>(h16, row_ptr, col, dinv, b1, agg, N);

  // ---- BN stats ----
  k_bnstats<<<1024, 256, 0, stream>>>(agg, stats, N);

  // ---- layer 2: BN+ReLU fused GEMM -> scaled bf16 table; gather ----
  k_gemm2<<<nb_t, 256, 0, stream>>>(agg, W2, dinv, stats, gamma, beta, h16, N, inv_n);
  k_gather_p<<<nb_n4, 256, 0, stream>>>(h16, row_ptr, col, dinv, b2, out, N);
}

// Round 11
// 327.393 us; speedup vs baseline: 1.0512x; 1.0312x over previous
//
#include <hip/hip_runtime.h>

#define BN_EPS 1e-5f
#define SCAN_CHUNK 2048
#define EPB 16384          // edges per sort block (256 thr x 64 edges)
#define NBUCK 512          // dst>>8 buckets (dst < 131072)
#define NBG 512            // persistent GEMM blocks

// ---------------- bf16 helpers ----------------
__device__ __forceinline__ float bf2f(unsigned short u) {
  return __uint_as_float(((unsigned)u) << 16);
}
__device__ __forceinline__ unsigned short f2bf(float f) {
  unsigned b = __float_as_uint(f);
  b += 0x7FFFu + ((b >> 16) & 1u);   // round-to-nearest-even
  return (unsigned short)(b >> 16);
}

// ---------------- persistent GEMM body: W in LDS, X reg-prefetched ----------
// Round-9 evidence: one-tile-per-block GEMM = 50us vs ~12us VALU floor,
// nothing saturated -> intra-block [load,barrier,compute] serialization.
// vmcnt is an ORDERED counter: in-loop global W loads would force any X
// prefetch to drain early -- so W is staged to LDS once per block, and each
// persistent block loops over tiles prefetching the NEXT tile's X into
// registers while computing the current one (T14 issue-early/write-late).
// FMA order and values identical to round 9.
template<int K, bool FUSE_BN, bool SCALE>
__device__ __forceinline__ void gemm_persist(
    float* __restrict__ Ws, float* __restrict__ Xs, float* __restrict__ bn_s,
    int tile0, int stride, int nT,
    const float* __restrict__ X, const float* __restrict__ W,
    const float* __restrict__ dinv, const float* __restrict__ stats,
    const float* __restrict__ gamma, const float* __restrict__ beta,
    unsigned short* __restrict__ Y, int n, float inv_n) {
  constexpr int XS = K + 4;
  constexpr int RV = K / 4;
  constexpr int NL = (64 * RV) / 256;   // float4 loads per thread per tile
  const int t = threadIdx.x;

  if (FUSE_BN) {
    if (t < 64) {
      float mean = stats[t] * inv_n;
      float var = stats[64 + t] * inv_n - mean * mean;
      bn_s[t] = mean;
      bn_s[64 + t] = rsqrtf(var + BN_EPS) * gamma[t];
      bn_s[128 + t] = beta[t];
    }
  }
  // stage W into LDS once per block
  {
    const float4* wv = (const float4*)W;
    float4* wsv = (float4*)Ws;
    for (int idx = t; idx < K * 16; idx += 256) wsv[idx] = wv[idx];
  }

  const int tc = t & 15;
  const int tr = t >> 4;

  float4 xg[NL];
  int tile = tile0;
  // initial X load (tile0)
  {
    int base = tile * 64;
#pragma unroll
    for (int j = 0; j < NL; ++j) {
      int idx = t + j * 256;
      int row = idx / RV, kk = idx % RV;
      float4 v = make_float4(0.f, 0.f, 0.f, 0.f);
      if (base + row < n) v = *(const float4*)(X + (size_t)(base + row) * K + kk * 4);
      xg[j] = v;
    }
  }
  __syncthreads();            // bn_s + Ws visible
  // write tile0 to LDS (BN transform at write time)
  {
    int base = tile * 64;
#pragma unroll
    for (int j = 0; j < NL; ++j) {
      int idx = t + j * 256;
      int row = idx / RV, kk = idx % RV;
      float4 v = xg[j];
      if (FUSE_BN && base + row < n) {
        int k0 = kk * 4;
        v.x = fmaxf(fmaf(v.x - bn_s[k0 + 0], bn_s[64 + k0 + 0], bn_s[128 + k0 + 0]), 0.f);
        v.y = fmaxf(fmaf(v.y - bn_s[k0 + 1], bn_s[64 + k0 + 1], bn_s[128 + k0 + 1]), 0.f);
        v.z = fmaxf(fmaf(v.z - bn_s[k0 + 2], bn_s[64 + k0 + 2], bn_s[128 + k0 + 2]), 0.f);
        v.w = fmaxf(fmaf(v.w - bn_s[k0 + 3], bn_s[64 + k0 + 3], bn_s[128 + k0 + 3]), 0.f);
      }
      *(float4*)(Xs + row * XS + kk * 4) = v;
    }
  }
  __syncthreads();

  for (;;) {
    const int next = tile + stride;
    const bool havenext = (next < nT);
    if (havenext) {               // prefetch next tile's X; used only after barrier
      int nb2 = next * 64;
#pragma unroll
      for (int j = 0; j < NL; ++j) {
        int idx = t + j * 256;
        int row = idx / RV, kk = idx % RV;
        float4 v = make_float4(0.f, 0.f, 0.f, 0.f);
        if (nb2 + row < n) v = *(const float4*)(X + (size_t)(nb2 + row) * K + kk * 4);
        xg[j] = v;
      }
    }

    // ---- compute current tile (Xs/Ws via LDS only) ----
    float acc[4][4];
#pragma unroll
    for (int r = 0; r < 4; ++r)
#pragma unroll
      for (int c = 0; c < 4; ++c) acc[r][c] = 0.f;

#pragma unroll 4
    for (int k = 0; k < K; k += 4) {
      float4 xr[4], wr[4];
#pragma unroll
      for (int r = 0; r < 4; ++r) xr[r] = *(const float4*)(Xs + (tr * 4 + r) * XS + k);
#pragma unroll
      for (int kk = 0; kk < 4; ++kk) wr[kk] = *(const float4*)(Ws + (k + kk) * 64 + tc * 4);
#pragma unroll
      for (int kk = 0; kk < 4; ++kk) {
#pragma unroll
        for (int r = 0; r < 4; ++r) {
          float xv = (kk == 0) ? xr[r].x : (kk == 1) ? xr[r].y : (kk == 2) ? xr[r].z : xr[r].w;
          acc[r][0] = fmaf(xv, wr[kk].x, acc[r][0]);
          acc[r][1] = fmaf(xv, wr[kk].y, acc[r][1]);
          acc[r][2] = fmaf(xv, wr[kk].z, acc[r][2]);
          acc[r][3] = fmaf(xv, wr[kk].w, acc[r][3]);
        }
      }
    }

    {
      int base = tile * 64;
#pragma unroll
      for (int r = 0; r < 4; ++r) {
        int i = base + tr * 4 + r;
        if (i < n) {
          float sc = SCALE ? dinv[i] : 1.0f;
          ushort4 o;
          o.x = f2bf(acc[r][0] * sc);
          o.y = f2bf(acc[r][1] * sc);
          o.z = f2bf(acc[r][2] * sc);
          o.w = f2bf(acc[r][3] * sc);
          *(ushort4*)(Y + (size_t)i * 64 + tc * 4) = o;
        }
      }
    }

    if (!havenext) break;
    __syncthreads();            // all waves done reading Xs
    {
      int nb2 = next * 64;
#pragma unroll
      for (int j = 0; j < NL; ++j) {
        int idx = t + j * 256;
        int row = idx / RV, kk = idx % RV;
        float4 v = xg[j];
        if (FUSE_BN && nb2 + row < n) {
          int k0 = kk * 4;
          v.x = fmaxf(fmaf(v.x - bn_s[k0 + 0], bn_s[64 + k0 + 0], bn_s[128 + k0 + 0]), 0.f);
          v.y = fmaxf(fmaf(v.y - bn_s[k0 + 1], bn_s[64 + k0 + 1], bn_s[128 + k0 + 1]), 0.f);
          v.z = fmaxf(fmaf(v.z - bn_s[k0 + 2], bn_s[64 + k0 + 2], bn_s[128 + k0 + 2]), 0.f);
          v.w = fmaxf(fmaf(v.w - bn_s[k0 + 3], bn_s[64 + k0 + 3], bn_s[128 + k0 + 3]), 0.f);
        }
        *(float4*)(Xs + row * XS + kk * 4) = v;
      }
    }
    __syncthreads();
    tile = next;
  }
}

// ---------------- fused: bucket histogram (LDS-only atomics) || persistent GEMM1 ----
// Round 2/3 evidence: global atomic-with-return executes memory-side (32B
// fabric RMW per op, ~1.1 TB/s wall). Counting sort instead.
__global__ __launch_bounds__(256) void k_fused_hist_gemm1(
    const int* __restrict__ dst, int* __restrict__ bh, int E, int nba,
    const float* __restrict__ X, const float* __restrict__ W,
    unsigned short* __restrict__ Y, int n, int nT) {
  __shared__ float Ws[128 * 64];
  __shared__ float Xs[64 * 132];

  if ((int)blockIdx.x < nba) {
    int* hist = (int*)Xs;                 // overlay: role-exclusive
    const int t = threadIdx.x;
    const int idx = blockIdx.x;
    for (int b = t; b < NBUCK; b += 256) hist[b] = 0;
    __syncthreads();
    int ebase = idx * EPB;
#pragma unroll
    for (int i = 0; i < EPB / 1024; ++i) {
      int e = ebase + (i * 256 + t) * 4;
      if (e + 3 < E) {
        int4 d4 = *(const int4*)(dst + e);
        atomicAdd(&hist[d4.x >> 8], 1);
        atomicAdd(&hist[d4.y >> 8], 1);
        atomicAdd(&hist[d4.z >> 8], 1);
        atomicAdd(&hist[d4.w >> 8], 1);
      } else {
        for (int q = e; q < E && q < e + 4; ++q) atomicAdd(&hist[dst[q] >> 8], 1);
      }
    }
    __syncthreads();
    for (int b = t; b < NBUCK; b += 256) bh[(size_t)b * nba + idx] = hist[b];
    return;
  }
  int pid = blockIdx.x - nba;
  int stride = gridDim.x - nba;
  gemm_persist<128, false, false>(Ws, Xs, nullptr, pid, stride, nT,
                                  X, W, nullptr, nullptr, nullptr, nullptr,
                                  Y, n, 0.f);
}

// ---------------- parallel exclusive scan of the 512 x nba count matrix ------
__global__ __launch_bounds__(256) void k_bscan_local(int* __restrict__ a,
                                                     int* __restrict__ bsum, int M) {
  __shared__ int ts[256];
  int base = blockIdx.x * SCAN_CHUNK;
  int t = threadIdx.x;
  int idx0 = base + t * 8;
  int v[8];
  int s = 0;
#pragma unroll
  for (int k = 0; k < 8; ++k) {
    int i = idx0 + k;
    int d = (i < M) ? a[i] : 0;
    v[k] = s;
    s += d;
  }
  int val = s;
  ts[t] = val;
  __syncthreads();
#pragma unroll
  for (int off = 1; off < 256; off <<= 1) {
    int add = (t >= off) ? ts[t - off] : 0;
    __syncthreads();
    val += add;
    ts[t] = val;
    __syncthreads();
  }
  int excl = val - s;
#pragma unroll
  for (int k = 0; k < 8; ++k) {
    int i = idx0 + k;
    if (i < M) a[i] = excl + v[k];
  }
  if (t == 255) bsum[blockIdx.x] = val;
}

__global__ void k_bscan_blk(int* __restrict__ bsum, int nblk) {
  if (threadIdx.x == 0) {
    int run = 0;
    for (int i = 0; i < nblk; ++i) { int v = bsum[i]; bsum[i] = run; run += v; }
  }
}

__global__ __launch_bounds__(256) void k_bscan_add(int* __restrict__ a,
                                                   const int* __restrict__ bsum, int M) {
  int off = bsum[blockIdx.x];
  int base = blockIdx.x * SCAN_CHUNK;
  for (int k = threadIdx.x; k < SCAN_CHUNK; k += 256) {
    int i = base + k;
    if (i < M) a[i] += off;
  }
}

// ---------------- scatter edges into bucket-grouped order ----------------
__global__ __launch_bounds__(256) void k_scatter(
    const int* __restrict__ src, const int* __restrict__ dst,
    const int* __restrict__ bh, int* __restrict__ sval, int E, int nba) {
  __shared__ int cur[NBUCK];
  const int t = threadIdx.x;
  for (int b = t; b < NBUCK; b += 256) cur[b] = bh[(size_t)b * nba + blockIdx.x];
  __syncthreads();
  int ebase = blockIdx.x * EPB;
#pragma unroll
  for (int i = 0; i < EPB / 1024; ++i) {
    int e = ebase + (i * 256 + t) * 4;
    if (e + 3 < E) {
      int4 d4 = *(const int4*)(dst + e);
      int4 s4 = *(const int4*)(src + e);
      int p0 = atomicAdd(&cur[d4.x >> 8], 1);
      int p1 = atomicAdd(&cur[d4.y >> 8], 1);
      int p2 = atomicAdd(&cur[d4.z >> 8], 1);
      int p3 = atomicAdd(&cur[d4.w >> 8], 1);
      sval[p0] = s4.x | ((d4.x & 255) << 20);
      sval[p1] = s4.y | ((d4.y & 255) << 20);
      sval[p2] = s4.z | ((d4.z & 255) << 20);
      sval[p3] = s4.w | ((d4.w & 255) << 20);
    } else {
      for (int q = e; q < E && q < e + 4; ++q) {
        int d = dst[q];
        int p = atomicAdd(&cur[d >> 8], 1);
        sval[p] = src[q] | ((d & 255) << 20);
      }
    }
  }
}

// ---------------- exact per-node degree: one block per bucket ----------------
__global__ __launch_bounds__(256) void k_group_deg(
    const int* __restrict__ sval, const int* __restrict__ bh,
    int* __restrict__ deg, int nba, int n) {
  __shared__ int cnt[256];
  const int t = threadIdx.x;
  const int b = blockIdx.x;
  cnt[t] = 0;
  __syncthreads();
  int lo = bh[(size_t)b * nba];
  int end = bh[(size_t)(b + 1) * nba];
  for (int i = lo + t; i < end; i += 256)
    atomicAdd(&cnt[(sval[i] >> 20) & 255], 1);
  __syncthreads();
  int node = b * 256 + t;
  if (node < n) deg[node] = cnt[t];
}

// ---------------- exclusive scan (deg -> row_ptr), fused dinv ----------------

__global__ __launch_bounds__(256) void k_scan_local(const int* __restrict__ deg,
                                                    int* __restrict__ row_ptr,
                                                    int* __restrict__ blksum,
                                                    float* __restrict__ dinv, int n) {
  __shared__ int ts[256];
  int base = blockIdx.x * SCAN_CHUNK;
  int t = threadIdx.x;
  int idx0 = base + t * 8;
  int v[8];
  int s = 0;
#pragma unroll
  for (int k = 0; k < 8; ++k) {
    int i = idx0 + k;
    int d = (i < n) ? deg[i] : 0;
    if (i < n) dinv[i] = rsqrtf(1.0f + (float)d);   // self-loop included
    v[k] = s;
    s += d;
  }
  int val = s;
  ts[t] = val;
  __syncthreads();
#pragma unroll
  for (int off = 1; off < 256; off <<= 1) {
    int add = (t >= off) ? ts[t - off] : 0;
    __syncthreads();
    val += add;
    ts[t] = val;
    __syncthreads();
  }
  int excl = val - s;
#pragma unroll
  for (int k = 0; k < 8; ++k) {
    int i = idx0 + k;
    if (i < n) row_ptr[i] = excl + v[k];
  }
  if (t == 255) blksum[blockIdx.x] = val;
}

__global__ void k_scan_blk(int* __restrict__ blksum, int nblk,
                           int* __restrict__ row_ptr, int n,
                           float* __restrict__ stats) {
  for (int i = threadIdx.x; i < 128; i += 64) stats[i] = 0.f;   // fused BN-stats zero
  if (threadIdx.x == 0) {
    int run = 0;
    for (int i = 0; i < nblk; ++i) { int v = blksum[i]; blksum[i] = run; run += v; }
    row_ptr[n] = run;
  }
}

__global__ __launch_bounds__(256) void k_scan_add(int* __restrict__ row_ptr,
                                                  const int* __restrict__ blksum, int n) {
  int off = blksum[blockIdx.x];
  int base = blockIdx.x * SCAN_CHUNK;
  for (int k = threadIdx.x; k < SCAN_CHUNK; k += 256) {
    int i = base + k;
    if (i < n) row_ptr[i] += off;
  }
}

// ---------------- fused: CSR fill (per-bucket, LDS cursors) || table row-scale ----
__global__ __launch_bounds__(256) void k_fused_fill_scale(
    const int* __restrict__ sval, const int* __restrict__ bh,
    const int* __restrict__ row_ptr, int* __restrict__ col, int nba, int nbu,
    unsigned short* __restrict__ h16, const float* __restrict__ dinv, int n) {
  __shared__ int cur[256];
  const int t = threadIdx.x;
  if ((int)blockIdx.x < nbu) {
    const int b = blockIdx.x;
    int node = b * 256 + t;
    cur[t] = (node < n) ? row_ptr[node] : 0;
    __syncthreads();
    int lo = bh[(size_t)b * nba];
    int end = bh[(size_t)(b + 1) * nba];
    for (int i = lo + t; i < end; i += 256) {
      int v = sval[i];
      int p = atomicAdd(&cur[(v >> 20) & 255], 1);
      col[p] = v & 0x1FFFF;
    }
    return;
  }
  int si = blockIdx.x - nbu;
  int idx = (si * 256 + t) * 8;
  if (idx >= n * 64) return;
  int row = idx >> 6;
  float di = dinv[row];
  uint4 v = *(const uint4*)(h16 + idx);
  unsigned r[4] = {v.x, v.y, v.z, v.w};
#pragma unroll
  for (int q = 0; q < 4; ++q) {
    float lo = bf2f((unsigned short)(r[q] & 0xFFFFu)) * di;
    float hi = bf2f((unsigned short)(r[q] >> 16)) * di;
    r[q] = ((unsigned)f2bf(hi) << 16) | f2bf(lo);
  }
  *(uint4*)(h16 + idx) = make_uint4(r[0], r[1], r[2], r[3]);
}

// ---------------- gather: round-6 semantics, pipelined loads ----------------
__global__ __launch_bounds__(256) void k_gather_p(
    const unsigned short* __restrict__ Hs,
    const int* __restrict__ row_ptr,
    const int* __restrict__ col,
    const float* __restrict__ dinv,
    const float* __restrict__ b,
    float* __restrict__ out, int n) {
  const uint2* H64 = (const uint2*)Hs;
  int lane = threadIdx.x & 63;
  int wv = threadIdx.x >> 6;
  int i = blockIdx.x * 4 + wv;
  if (i >= n) return;
  int quarter = lane >> 4;
  int q = lane & 15;
  int p0 = row_ptr[i], p1 = row_ptr[i + 1];
  int nl = p1 - p0;
  int L = nl + 1;                       // self + neighbors
  int cl = (lane == 0) ? i : ((lane <= nl) ? col[p0 + lane - 1] : i);
  int Lc = (L < 32) ? L : 32;
  bool two = (Lc > 16);                 // wave-uniform

  uint2 u[8];
  float ww[8];
#pragma unroll
  for (int s = 0; s < 4; ++s) {         // round 0: vidx 0..15
    int vidx = quarter * 4 + s;
    int vc = (vidx < Lc) ? vidx : 0;    // clamp to self (L1-hit dup)
    int c = __shfl(cl, vc);
    u[s] = H64[(size_t)c * 16 + q];
    ww[s] = (vidx < Lc) ? 1.0f : 0.0f;
  }
  if (two) {
#pragma unroll
    for (int s = 4; s < 8; ++s) {       // round 1: vidx 16..31
      int vidx = 16 + quarter * 4 + (s - 4);
      int vc = (vidx < Lc) ? vidx : 0;
      int c = __shfl(cl, vc);
      u[s] = H64[(size_t)c * 16 + q];
      ww[s] = (vidx < Lc) ? 1.0f : 0.0f;
    }
  }

  float a0 = 0.f, a1 = 0.f, a2 = 0.f, a3 = 0.f;
#pragma unroll
  for (int s = 0; s < 4; ++s) {
    a0 = fmaf(ww[s], bf2f((unsigned short)u[s].x), a0);
    a1 = fmaf(ww[s], bf2f((unsigned short)(u[s].x >> 16)), a1);
    a2 = fmaf(ww[s], bf2f((unsigned short)u[s].y), a2);
    a3 = fmaf(ww[s], bf2f((unsigned short)(u[s].y >> 16)), a3);
  }
  if (two) {
#pragma unroll
    for (int s = 4; s < 8; ++s) {
      a0 = fmaf(ww[s], bf2f((unsigned short)u[s].x), a0);
      a1 = fmaf(ww[s], bf2f((unsigned short)(u[s].x >> 16)), a1);
      a2 = fmaf(ww[s], bf2f((unsigned short)u[s].y), a2);
      a3 = fmaf(ww[s], bf2f((unsigned short)(u[s].y >> 16)), a3);
    }
  }
  for (int v = 32 + quarter; v < L; v += 4) {   // rare: degree > 31
    int c = col[p0 + v - 1];
    uint2 uu = H64[(size_t)c * 16 + q];
    a0 += bf2f((unsigned short)uu.x);
    a1 += bf2f((unsigned short)(uu.x >> 16));
    a2 += bf2f((unsigned short)uu.y);
    a3 += bf2f((unsigned short)(uu.y >> 16));
  }
  a0 += __shfl_down(a0, 16); a0 += __shfl_down(a0, 32);
  a1 += __shfl_down(a1, 16); a1 += __shfl_down(a1, 32);
  a2 += __shfl_down(a2, 16); a2 += __shfl_down(a2, 32);
  a3 += __shfl_down(a3, 16); a3 += __shfl_down(a3, 32);
  if (lane < 16) {
    float di = dinv[i];
    float4 bb = *(const float4*)(b + 4 * q);
    float4 o;
    o.x = fmaf(di, a0, bb.x);
    o.y = fmaf(di, a1, bb.y);
    o.z = fmaf(di, a2, bb.z);
    o.w = fmaf(di, a3, bb.w);
    *(float4*)(out + (size_t)i * 64 + 4 * q) = o;
  }
}

// ---------------- BatchNorm stats (separate pass) ----------------
__global__ __launch_bounds__(256) void k_bnstats(const float* __restrict__ A,
                                                 float* __restrict__ stats, int n) {
  int j = threadIdx.x & 63;
  int r = threadIdx.x >> 6;
  float s = 0.f, s2 = 0.f;
  for (int i = blockIdx.x * 4 + r; i < n; i += gridDim.x * 4) {
    float v = A[(size_t)i * 64 + j];
    s += v;
    s2 += v * v;
  }
  __shared__ float ls[256], ls2[256];
  ls[threadIdx.x] = s;
  ls2[threadIdx.x] = s2;
  __syncthreads();
  if (threadIdx.x < 64) {
    atomicAdd(&stats[j], ls[j] + ls[j + 64] + ls[j + 128] + ls[j + 192]);
    atomicAdd(&stats[64 + j], ls2[j] + ls2[j + 64] + ls2[j + 128] + ls2[j + 192]);
  }
}

// ---------------- GEMM2 persistent (BN+ReLU fused input, dinv-scaled output) --
__global__ __launch_bounds__(256) void k_gemm2(const float* __restrict__ X,
                                               const float* __restrict__ W,
                                               const float* __restrict__ dinv,
                                               const float* __restrict__ stats,
                                               const float* __restrict__ gamma,
                                               const float* __restrict__ beta,
                                               unsigned short* __restrict__ Y,
                                               int n, float inv_n, int nT) {
  __shared__ float Ws[64 * 64];
  __shared__ float Xs[64 * 68];
  __shared__ float bn_s[192];
  gemm_persist<64, true, true>(Ws, Xs, bn_s, blockIdx.x, gridDim.x, nT,
                               X, W, dinv, stats, gamma, beta, Y, n, inv_n);
}

// ---------------- launch ----------------

extern "C" void kernel_launch(void* const* d_in, const int* in_sizes, int n_in,
                              void* d_out, int out_size, void* d_ws, size_t ws_size,
                              hipStream_t stream) {
  const float* x     = (const float*)d_in[0];
  const int*   ei    = (const int*)d_in[1];
  const float* W1    = (const float*)d_in[2];
  const float* b1    = (const float*)d_in[3];
  const float* W2    = (const float*)d_in[4];
  const float* b2    = (const float*)d_in[5];
  const float* gamma = (const float*)d_in[6];
  const float* beta  = (const float*)d_in[7];
  float* out = (float*)d_out;

  const int N = in_sizes[0] / 128;   // 100000
  const int E = in_sizes[1] / 2;     // 1600000
  const int* src = ei;
  const int* dst = ei + E;

  const size_t Npad = ((size_t)N + 256) & ~(size_t)255;

  // workspace layout (identical footprint to previous rounds)
  char* p = (char*)d_ws;
  float* dinv    = (float*)p;               p += Npad * 4;
  int*   deg     = (int*)p;                 p += Npad * 4;
  int*   row_ptr = (int*)p;                 p += Npad * 4;
  int*   blksum  = (int*)p;                 p += 256 * 4;
  int*   sval    = (int*)p;                 p += (size_t)E * 4;   // bucket-grouped edges
  int*   col     = (int*)p;                 p += (size_t)E * 4;
  unsigned short* h16 = (unsigned short*)p; p += (size_t)N * 64 * 2;  // bf16 table
  float* agg     = (float*)p;               p += (size_t)N * 64 * 4;
  float* stats   = (float*)p;               p += 128 * 4;

  // bh aliases agg: bh dies after k_fused_fill_scale, agg born at gather1.
  int* bh = (int*)agg;                      // NBUCK * nba ints (~200 KB)

  int nb_n4 = (N + 3) / 4;
  int nb_t  = (N + 63) / 64;
  int nba   = (E + EPB - 1) / EPB;               // sort blocks (98)
  int nbu   = (N + 255) / 256;                   // used buckets (391)
  int nbS   = (N * 64 + 2047) / 2048;            // 8 bf16 elems/thread
  int nscan = (N + SCAN_CHUNK - 1) / SCAN_CHUNK;
  int M     = NBUCK * nba;                       // count-matrix size (50176)
  int nbM   = (M + SCAN_CHUNK - 1) / SCAN_CHUNK; // 25 blocks
  float inv_n = 1.0f / (float)N;

  // ---- fused: bucket histogram || persistent GEMM1 ----
  k_fused_hist_gemm1<<<nba + NBG, 256, 0, stream>>>(dst, bh, E, nba,
                                                    x, W1, h16, N, nb_t);

  // ---- counting sort: 3-phase parallel scan of count matrix, then scatter ----
  k_bscan_local<<<nbM, 256, 0, stream>>>(bh, blksum, M);
  k_bscan_blk<<<1, 64, 0, stream>>>(blksum, nbM);
  k_bscan_add<<<nbM, 256, 0, stream>>>(bh, blksum, M);
  k_scatter<<<nba, 256, 0, stream>>>(src, dst, bh, sval, E, nba);

  // ---- exact per-node degree (no global atomics) ----
  k_group_deg<<<nbu, 256, 0, stream>>>(sval, bh, deg, nba, N);

  // ---- CSR scan (dinv fused; stats zero fused) ----
  k_scan_local<<<nscan, 256, 0, stream>>>(deg, row_ptr, blksum, dinv, N);
  k_scan_blk<<<1, 64, 0, stream>>>(blksum, nscan, row_ptr, N, stats);
  k_scan_add<<<nscan, 256, 0, stream>>>(row_ptr, blksum, N);

  // ---- fused: CSR fill (bucket-local) || table row-scale ----
  k_fused_fill_scale<<<nbu + nbS, 256, 0, stream>>>(sval, bh, row_ptr, col,
                                                    nba, nbu, h16, dinv, N);

  // ---- layer 1 aggregation (pipelined loads, shfl col cache) ----
  k_gather_p<<<nb_n4, 256, 0, stream>>>(h16, row_ptr, col, dinv, b1, agg, N);

  // ---- BN stats ----
  k_bnstats<<<1024, 256, 0, stream>>>(agg, stats, N);

  // ---- layer 2: persistent BN+ReLU fused GEMM -> scaled bf16 table; gather ----
  k_gemm2<<<NBG, 256, 0, stream>>>(agg, W2, dinv, stats, gamma, beta, h16, N,
                                   inv_n, nb_t);
  k_gather_p<<<nb_n4, 256, 0, stream>>>(h16, row_ptr, col, dinv, b2, out, N);
}